// Round 1
// baseline (284.030 us; speedup 1.0000x reference)
//
#include <hip/hip_runtime.h>
#include <hip/hip_bf16.h>

// GAT 2-layer, but reference returns h[0] only (128 floats).
// => compute only the 2-hop in-neighborhood slice of node 0.
//
// Pipeline (all on `stream`, device-driven counts, graph-capture safe):
//  k_init    : zero marks + counters
//  k_scan1   : find edges with dst==0 (+ self loop (0,0))        -> L1
//  k_buildU1 : unique srcs of L1                                  -> U1, mark1
//  k_scan2   : find edges with dst in U1 (+ self loops for U1)    -> L2
//  k_buildU2 : unique srcs of L2                                  -> U2, mark2
//  k_mm1     : h1proj[u] = x[u] @ W1 (per U2), + attn logits a_s1/a_d1
//  k_agg1    : per U1 node: leakyrelu + softmax over in-edges, aggregate,
//              + b1, ReLU                                         -> h1
//  k_mm2     : h2proj[v] = h1[v] @ W2 (per U1), + attn logits a_s2/a_d2
//  k_final   : softmax over in-edges of node 0, aggregate, + b2   -> d_out

#define NEG_SLOPE 0.2f

constexpr int INDIM = 768;
constexpr int HEADS = 4;
constexpr int HID   = 128;
constexpr int HD    = HEADS * HID;  // 512
constexpr int OUTD  = 128;

constexpr int MAXL1 = 512;    // edges into node 0 (expected ~11)
constexpr int MAXU1 = 512;    // unique 1-hop sources (<= MAXL1)
constexpr int MAXL2 = 4096;   // edges into U1 (expected ~130)
constexpr int MAXU2 = 2048;   // unique 2-hop sources (expected ~130)
constexpr int CAPE  = 512;    // per-node in-edge cap in k_agg1

__global__ void k_init(int* counters, int* mark1, int* mark2, int n) {
  int i = blockIdx.x * blockDim.x + threadIdx.x;
  if (i < 8) counters[i] = 0;
  if (i < n) { mark1[i] = 0; mark2[i] = 0; }
}

__global__ void k_scan1(const int* __restrict__ src, const int* __restrict__ dst,
                        int E, int* counters, int* L1src) {
  int e = blockIdx.x * blockDim.x + threadIdx.x;
  if (e < E && dst[e] == 0) {
    int p = atomicAdd(&counters[0], 1);
    if (p < MAXL1) L1src[p] = src[e];
  }
  if (e == 0) {  // self loop (0,0)
    int p = atomicAdd(&counters[0], 1);
    if (p < MAXL1) L1src[p] = 0;
  }
}

__global__ void k_buildU1(int* counters, const int* __restrict__ L1src,
                          int* U1, int* mark1) {
  int i = blockIdx.x * blockDim.x + threadIdx.x;
  int n = min(counters[0], MAXL1);
  if (i < n) {
    int v = L1src[i];
    if (atomicCAS(&mark1[v], 0, -1) == 0) {
      int idx = atomicAdd(&counters[1], 1);
      U1[idx] = v;                    // idx < n <= MAXU1
      atomicExch(&mark1[v], idx + 1);
    }
  }
}

__global__ void k_scan2(const int* __restrict__ src, const int* __restrict__ dst,
                        int E, int* counters, const int* __restrict__ U1,
                        const int* __restrict__ mark1, int* L2src, int* L2dst) {
  int e = blockIdx.x * blockDim.x + threadIdx.x;
  if (e < E) {
    int d = dst[e];
    if (mark1[d] > 0) {
      int p = atomicAdd(&counters[2], 1);
      if (p < MAXL2) { L2src[p] = src[e]; L2dst[p] = d; }
    }
  }
  int nu1 = min(counters[1], MAXU1);   // finalized by k_buildU1
  if (e < nu1) {                        // self loops for U1 nodes
    int v = U1[e];
    int p = atomicAdd(&counters[2], 1);
    if (p < MAXL2) { L2src[p] = v; L2dst[p] = v; }
  }
}

__global__ void k_buildU2(int* counters, const int* __restrict__ L2src,
                          int* U2, int* mark2) {
  int i = blockIdx.x * blockDim.x + threadIdx.x;
  int n = min(counters[2], MAXL2);
  if (i < n) {
    int v = L2src[i];
    if (atomicCAS(&mark2[v], 0, -1) == 0) {
      int idx = atomicAdd(&counters[3], 1);
      if (idx < MAXU2) U2[idx] = v;
      atomicExch(&mark2[v], idx + 1);
    }
  }
}

// grid: (MAXU2, HEADS), block: 128.  One block = one (node, head) 128-col chunk.
__global__ void k_mm1(const float* __restrict__ x, const float* __restrict__ W1,
                      const float* __restrict__ a_s1, const float* __restrict__ a_d1,
                      const int* __restrict__ counters, const int* __restrict__ U2,
                      float* h1proj, float* as1, float* ad1) {
  int bu = blockIdx.x, h = blockIdx.y;
  int n = min(counters[3], MAXU2);
  if (bu >= n) return;
  int u = U2[bu];
  __shared__ float xs[INDIM];
  int t = threadIdx.x;  // 128
  for (int k = t; k < INDIM; k += 128) xs[k] = x[(size_t)u * INDIM + k];
  __syncthreads();
  const float* w = W1 + (size_t)h * HID + t;  // W1[k][h*128+t], row-major [768,512]
  float a0 = 0.f, a1 = 0.f, a2 = 0.f, a3 = 0.f;
  for (int k = 0; k < INDIM; k += 4) {
    a0 += xs[k + 0] * w[(size_t)(k + 0) * HD];
    a1 += xs[k + 1] * w[(size_t)(k + 1) * HD];
    a2 += xs[k + 2] * w[(size_t)(k + 2) * HD];
    a3 += xs[k + 3] * w[(size_t)(k + 3) * HD];
  }
  float acc = (a0 + a1) + (a2 + a3);
  h1proj[(size_t)bu * HD + h * HID + t] = acc;
  // attention logits: alpha_s1[bu][h] = sum_d acc_d * a_src1[h][d]
  float ps = acc * a_s1[h * HID + t];
  float pd = acc * a_d1[h * HID + t];
  for (int off = 32; off > 0; off >>= 1) {
    ps += __shfl_down(ps, off);
    pd += __shfl_down(pd, off);
  }
  __shared__ float rs[2], rd[2];
  int wid = t >> 6, lane = t & 63;
  if (lane == 0) { rs[wid] = ps; rd[wid] = pd; }
  __syncthreads();
  if (t == 0) {
    as1[bu * HEADS + h] = rs[0] + rs[1];
    ad1[bu * HEADS + h] = rd[0] + rd[1];
  }
}

// grid: MAXU1, block: 128.  One block = one destination node v in U1.
__global__ void k_agg1(const int* __restrict__ counters, const int* __restrict__ U1,
                       const int* __restrict__ mark2,
                       const int* __restrict__ L2src, const int* __restrict__ L2dst,
                       const float* __restrict__ as1, const float* __restrict__ ad1,
                       const float* __restrict__ h1proj, const float* __restrict__ b1,
                       float* h1) {
  int bv = blockIdx.x;
  int nu1 = min(counters[1], MAXU1);
  if (bv >= nu1) return;
  int v = U1[bv];
  int vslot = mark2[v] - 1;
  int nL2 = min(counters[2], MAXL2);
  __shared__ int es[CAPE];
  __shared__ float ee[CAPE][HEADS];
  __shared__ int ecount;
  __shared__ float m[HEADS], den[HEADS];
  int t = threadIdx.x;  // 128
  if (t == 0) ecount = 0;
  __syncthreads();
  for (int j = t; j < nL2; j += 128) {
    if (L2dst[j] == v) {
      int p = atomicAdd(&ecount, 1);
      if (p < CAPE) {
        int s2 = mark2[L2src[j]] - 1;
        es[p] = s2;
        #pragma unroll
        for (int h = 0; h < HEADS; h++) {
          float ev = as1[s2 * HEADS + h] + ad1[vslot * HEADS + h];
          ee[p][h] = ev > 0.f ? ev : NEG_SLOPE * ev;  // leaky_relu
        }
      }
    }
  }
  __syncthreads();
  int ne = min(ecount, CAPE);
  if (t < HEADS) {
    float mm = -1e30f;
    for (int j = 0; j < ne; j++) mm = fmaxf(mm, ee[j][t]);
    float s = 0.f;
    for (int j = 0; j < ne; j++) s += expf(ee[j][t] - mm);
    m[t] = mm;
    den[t] = s + 1e-16f;
  }
  __syncthreads();
  for (int idx = t; idx < ne * HEADS; idx += 128) {
    int j = idx / HEADS, h = idx % HEADS;
    ee[j][h] = expf(ee[j][h] - m[h]) / den[h];
  }
  __syncthreads();
  #pragma unroll
  for (int h = 0; h < HEADS; h++) {
    float acc = 0.f;
    for (int j = 0; j < ne; j++)
      acc += ee[j][h] * h1proj[(size_t)es[j] * HD + h * HID + t];
    acc += b1[h * HID + t];
    h1[(size_t)bv * HD + h * HID + t] = fmaxf(acc, 0.f);  // + b1, then ReLU
  }
}

// grid: MAXU1, block: 128.  h2proj[v] = h1[v] @ W2; attn logits.
__global__ void k_mm2(const int* __restrict__ counters, const float* __restrict__ h1,
                      const float* __restrict__ W2, const float* __restrict__ a_s2,
                      const float* __restrict__ a_d2,
                      float* h2proj, float* as2, float* ad2) {
  int bv = blockIdx.x;
  int nu1 = min(counters[1], MAXU1);
  if (bv >= nu1) return;
  __shared__ float hs[HD];
  int t = threadIdx.x;  // 128
  for (int k = t; k < HD; k += 128) hs[k] = h1[(size_t)bv * HD + k];
  __syncthreads();
  const float* w = W2 + t;  // W2[k][t], row-major [512,128]
  float a0 = 0.f, a1 = 0.f, a2 = 0.f, a3 = 0.f;
  for (int k = 0; k < HD; k += 4) {
    a0 += hs[k + 0] * w[(size_t)(k + 0) * OUTD];
    a1 += hs[k + 1] * w[(size_t)(k + 1) * OUTD];
    a2 += hs[k + 2] * w[(size_t)(k + 2) * OUTD];
    a3 += hs[k + 3] * w[(size_t)(k + 3) * OUTD];
  }
  float acc = (a0 + a1) + (a2 + a3);
  h2proj[(size_t)bv * OUTD + t] = acc;
  float ps = acc * a_s2[t];
  float pd = acc * a_d2[t];
  for (int off = 32; off > 0; off >>= 1) {
    ps += __shfl_down(ps, off);
    pd += __shfl_down(pd, off);
  }
  __shared__ float rs[2], rd[2];
  int wid = t >> 6, lane = t & 63;
  if (lane == 0) { rs[wid] = ps; rd[wid] = pd; }
  __syncthreads();
  if (t == 0) { as2[bv] = rs[0] + rs[1]; ad2[bv] = rd[0] + rd[1]; }
}

// 1 block, 128 threads: layer-2 softmax+aggregate at node 0.
__global__ void k_final(const int* __restrict__ counters, const int* __restrict__ L1src,
                        const int* __restrict__ mark1,
                        const float* __restrict__ as2, const float* __restrict__ ad2,
                        const float* __restrict__ h2proj, const float* __restrict__ b2,
                        float* __restrict__ out) {
  int t = threadIdx.x;  // 128
  int nL1 = min(counters[0], MAXL1);
  int slot0 = mark1[0] - 1;
  float ad = ad2[slot0];
  float mm = -1e30f;
  for (int j = 0; j < nL1; j++) {
    int sl = mark1[L1src[j]] - 1;
    float e = as2[sl] + ad;
    e = e > 0.f ? e : NEG_SLOPE * e;
    mm = fmaxf(mm, e);
  }
  float den = 0.f;
  for (int j = 0; j < nL1; j++) {
    int sl = mark1[L1src[j]] - 1;
    float e = as2[sl] + ad;
    e = e > 0.f ? e : NEG_SLOPE * e;
    den += expf(e - mm);
  }
  den += 1e-16f;
  float acc = 0.f;
  for (int j = 0; j < nL1; j++) {
    int sl = mark1[L1src[j]] - 1;
    float e = as2[sl] + ad;
    e = e > 0.f ? e : NEG_SLOPE * e;
    acc += (expf(e - mm) / den) * h2proj[(size_t)sl * OUTD + t];
  }
  out[t] = acc + b2[t];
}

extern "C" void kernel_launch(void* const* d_in, const int* in_sizes, int n_in,
                              void* d_out, int out_size, void* d_ws, size_t ws_size,
                              hipStream_t stream) {
  const float* x    = (const float*)d_in[0];
  const int*   ei   = (const int*)d_in[1];
  const float* W1   = (const float*)d_in[2];
  const float* a_s1 = (const float*)d_in[3];
  const float* a_d1 = (const float*)d_in[4];
  const float* b1   = (const float*)d_in[5];
  const float* W2   = (const float*)d_in[6];
  const float* a_s2 = (const float*)d_in[7];
  const float* a_d2 = (const float*)d_in[8];
  const float* b2   = (const float*)d_in[9];
  float* out = (float*)d_out;

  const int N = in_sizes[0] / INDIM;   // 50000
  const int E = in_sizes[1] / 2;       // 500000
  const int* src = ei;
  const int* dst = ei + E;

  // bump allocator on workspace (256B aligned)
  char* p = (char*)d_ws;
  auto alloc = [&](size_t bytes) -> void* {
    void* r = (void*)p;
    p += (bytes + 255) & ~(size_t)255;
    return r;
  };
  int* counters = (int*)alloc(8 * sizeof(int));
  int* L1src = (int*)alloc(MAXL1 * sizeof(int));
  int* U1    = (int*)alloc(MAXU1 * sizeof(int));
  int* L2src = (int*)alloc(MAXL2 * sizeof(int));
  int* L2dst = (int*)alloc(MAXL2 * sizeof(int));
  int* U2    = (int*)alloc(MAXU2 * sizeof(int));
  int* mark1 = (int*)alloc((size_t)N * sizeof(int));
  int* mark2 = (int*)alloc((size_t)N * sizeof(int));
  float* as1    = (float*)alloc((size_t)MAXU2 * HEADS * sizeof(float));
  float* ad1    = (float*)alloc((size_t)MAXU2 * HEADS * sizeof(float));
  float* h1proj = (float*)alloc((size_t)MAXU2 * HD * sizeof(float));
  float* h1     = (float*)alloc((size_t)MAXU1 * HD * sizeof(float));
  float* h2proj = (float*)alloc((size_t)MAXU1 * OUTD * sizeof(float));
  float* as2    = (float*)alloc(MAXU1 * sizeof(float));
  float* ad2    = (float*)alloc(MAXU1 * sizeof(float));

  k_init<<<(N + 255) / 256, 256, 0, stream>>>(counters, mark1, mark2, N);
  k_scan1<<<(E + 255) / 256, 256, 0, stream>>>(src, dst, E, counters, L1src);
  k_buildU1<<<(MAXL1 + 255) / 256, 256, 0, stream>>>(counters, L1src, U1, mark1);
  k_scan2<<<(E + 255) / 256, 256, 0, stream>>>(src, dst, E, counters, U1, mark1,
                                               L2src, L2dst);
  k_buildU2<<<(MAXL2 + 255) / 256, 256, 0, stream>>>(counters, L2src, U2, mark2);
  k_mm1<<<dim3(MAXU2, HEADS), 128, 0, stream>>>(x, W1, a_s1, a_d1, counters, U2,
                                                h1proj, as1, ad1);
  k_agg1<<<MAXU1, 128, 0, stream>>>(counters, U1, mark2, L2src, L2dst, as1, ad1,
                                    h1proj, b1, h1);
  k_mm2<<<MAXU1, 128, 0, stream>>>(counters, h1, W2, a_s2, a_d2, h2proj, as2, ad2);
  k_final<<<1, 128, 0, stream>>>(counters, L1src, mark1, as2, ad2, h2proj, b2, out);
}